// Round 17
// baseline (88.967 us; speedup 1.0000x reference)
//
#include <hip/hip_runtime.h>

#define N_NODES 10000
#define N_EDGES 160000
#define E_TOT   170000   // + self loops
#define H1      8
#define C1      120
#define F1      960      // H1*C1
#define BSTRIDE 64       // bucket slots per node (max in-degree ~45 << 64)

typedef _Float16 h2 __attribute__((ext_vector_type(2)));
typedef _Float16 f16x8 __attribute__((ext_vector_type(8)));
typedef float f32x4 __attribute__((ext_vector_type(4)));
union H2U { unsigned u; h2 h; };
union AU  { uint4 u; f16x8 h; };

#if defined(__has_builtin)
#if __has_builtin(__builtin_amdgcn_fdot2)
#define FDOT2(a,b,c) __builtin_amdgcn_fdot2((a),(b),(c),false)
#endif
#endif
#ifndef FDOT2
#define FDOT2(a,b,c) ((float)(a)[0]*(float)(b)[0] + (float)(a)[1]*(float)(b)[1] + (c))
#endif

__device__ __forceinline__ float lrelu(float v) { return fmaxf(v, 0.2f * v); }
__device__ __forceinline__ unsigned packh2(float a, float b) {
    H2U u; u.h = (h2){(_Float16)a, (_Float16)b}; return u.u;
}
__device__ __forceinline__ h2 toh2(unsigned v) { H2U u; u.u = v; return u.h; }

// ---------------- fused prep ----------------
// blocks 0..3: zero own Bp range; then t<240 (real channel rc = b*240+t,
//   heads 2b/2b+1): |0.4*att| folded into f16 weights/bias; channels sorted
//   positives-first within head (newu via deterministic rank); Bh[h] = #pos.
//   Also WAh/PBh (orig order, unscaled) and W2P (t<120).
// blocks 4..43: P (x0.6) in-block; 250 nodes each: xh pack, Ls, Lr
// blocks 44..83: zero cnt (bucket counters)
__global__ __launch_bounds__(256) void prep(
        const float* __restrict__ x,
        const float* __restrict__ W1l, const float* __restrict__ W1r,
        const float* __restrict__ b1l, const float* __restrict__ b1r,
        const float* __restrict__ att1, const float* __restrict__ bias1,
        const float* __restrict__ W2l, const float* __restrict__ W2r,
        uint4* __restrict__ BpH, int* __restrict__ Bh,
        uint2* __restrict__ WAh, unsigned* __restrict__ PBh,
        uint4* __restrict__ W2P,
        uint2* __restrict__ xh, float* __restrict__ Ls, float* __restrict__ Lr,
        int* __restrict__ cnt) {
    int b = blockIdx.x, t = threadIdx.x;
    if (b >= 44) {
        int i = (b - 44) * 256 + t;
        if (i < N_NODES) cnt[i] = 0;
        return;
    }
    if (b < 4) {
        // phase 0: zero this block's Bp range (512 uint4)
        BpH[b*512 + t]       = make_uint4(0u,0u,0u,0u);
        BpH[b*512 + 256 + t] = make_uint4(0u,0u,0u,0u);
        __syncthreads();
        if (t < 240) {
            int rc = b * 240 + t;
            int h = rc / C1, u = rc - h * C1;
            float a = att1[rc];
            int cntPos = 0, rankB = 0;
            for (int v = 0; v < C1; ++v) {
                bool pos = att1[h*C1 + v] > 0.f;
                cntPos += pos ? 1 : 0;
                rankB  += (v < u && pos) ? 1 : 0;
            }
            int newu = (a > 0.f) ? rankB : (cntPos + (u - rankB));
            float sc = fabsf(0.4f * a);
            float wl0 = W1l[rc], wl1 = W1l[F1+rc], wl2 = W1l[2*F1+rc], wl3 = W1l[3*F1+rc];
            float wr0 = W1r[rc], wr1 = W1r[F1+rc], wr2 = W1r[2*F1+rc], wr3 = W1r[3*F1+rc];
            float bc = b1l[rc] + b1r[rc];
            int pc2 = h * 128 + newu;
            int ct = pc2 >> 4, cl = pc2 & 15;
            BpH[ct*32 + cl] = make_uint4(packh2(sc*wl0, sc*wl1), packh2(sc*wl2, sc*wl3),
                                         packh2(sc*wr0, sc*wr1), packh2(sc*wr2, sc*wr3));
            BpH[ct*32 + 16 + cl] = make_uint4(packh2(sc*bc, 0.f), 0u, 0u, 0u);
            if (u == 0) Bh[h] = cntPos;
            // original-order unscaled tables for fused_agg1
            WAh[rc] = make_uint2(packh2(wl0, wl1), packh2(wl2, wl3));
            PBh[rc] = packh2(b1l[rc], bias1[rc]);
        }
        if (t < 120) {
            int i = b * 120 + t;          // pair index: h = i/60, u = i%60
            int h = i / 60, u = i - h * 60;
            int c0 = h * C1 + u, c1 = c0 + 60;
            const float4 wl0 = ((const float4*)W2l)[c0], wl1 = ((const float4*)W2l)[c1];
            const float4 wr0 = ((const float4*)W2r)[c0], wr1 = ((const float4*)W2r)[c1];
            W2P[i*2]   = make_uint4(packh2(wl0.x, wl1.x), packh2(wl0.y, wl1.y),
                                    packh2(wl0.z, wl1.z), packh2(wl0.w, wl1.w));
            W2P[i*2+1] = make_uint4(packh2(wr0.x, wr1.x), packh2(wr0.y, wr1.y),
                                    packh2(wr0.z, wr1.z), packh2(wr0.w, wr1.w));
        }
        return;
    }
    __shared__ float Ps[72];
    if (t < 72) {
        int h = t / 9, j = t % 9;
        float acc = 0.f;
        for (int u = 0; u < C1; ++u) {
            int c = h * C1 + u;
            float a = att1[c];
            float w;
            if (j < 4)      w = W1l[j * F1 + c];
            else if (j < 8) w = W1r[(j - 4) * F1 + c];
            else            w = b1l[c] + b1r[c];
            acc = fmaf(a, w, acc);
        }
        Ps[t] = 0.6f * acc;
    }
    __syncthreads();
    int n = (b - 4) * 250 + t;
    if (t < 250) {
        float4 xv = ((const float4*)x)[n];
        xh[n] = make_uint2(packh2(xv.x, xv.y), packh2(xv.z, xv.w));
#pragma unroll
        for (int h = 0; h < H1; ++h) {
            const float* p = Ps + h * 9;
            Ls[n*8+h] = xv.x*p[0] + xv.y*p[1] + xv.z*p[2] + xv.w*p[3];
            Lr[n*8+h] = xv.x*p[4] + xv.y*p[5] + xv.z*p[6] + xv.w*p[7] + p[8];
        }
    }
}

// ---------------- layer-1 logits: LDS-staged K=32 MFMA, 4 edge-frags/wave ----------------
// 512-thread blocks (8 waves, 512 edges; 64 edges/wave). Block stages the
// |att|-folded sorted weight table (32KB) in LDS. Per tile: 1 ds_read_b128 +
// 4 MFMA + sign-select epilogue (sign = posInHead < Bh[h], SGPR compare).
// Bucket fill fused (512 edges/block, one per thread).

__global__ __launch_bounds__(512) void logits_mfma(
        const int* __restrict__ ei, const uint2* __restrict__ xh,
        const uint4* __restrict__ BpH, const int* __restrict__ Bh,
        const float* __restrict__ Ls, const float* __restrict__ Lr,
        int* __restrict__ cnt, int* __restrict__ elist, int* __restrict__ slist,
        float* __restrict__ e1) {
    __shared__ uint4 BpL[2048];   // 32 KB
    int tid = threadIdx.x;
#pragma unroll
    for (int i = 0; i < 4; ++i) BpL[tid + i*512] = BpH[tid + i*512];
    // fused bucket fill (independent work; all threads reach the barrier)
    {
        int ef = blockIdx.x * 512 + tid;
        if (ef < E_TOT) {
            int s, d;
            if (ef < N_EDGES) { s = ei[ef]; d = ei[N_EDGES + ef]; }
            else { s = ef - N_EDGES; d = s; }
            int pos = atomicAdd(&cnt[d], 1);
            int slot = d * BSTRIDE + pos;
            elist[slot] = ef;
            slist[slot] = s;
        }
    }
    __syncthreads();

    int ebase = blockIdx.x * 512 + (tid >> 6) * 64;
    if (ebase >= E_TOT) return;
    int lane = tid & 63;
    int cl = lane & 15, g = lane >> 4;
    int g4 = g * 4;

    AU zu0, zu1, zu2, zu3;             // B-fragments: col = edge
    zu0.u = zu1.u = zu2.u = zu3.u = make_uint4(0u,0u,0u,0u);
    if (g == 0) {
#pragma unroll
        for (int f = 0; f < 4; ++f) {
            int er = ebase + f*16 + cl;
            if (er >= E_TOT) er = E_TOT - 1;
            int s, d;
            if (er < N_EDGES) { s = ei[er]; d = ei[N_EDGES + er]; }
            else { s = er - N_EDGES; d = s; }
            uint2 a = xh[s], b = xh[d];
            uint4 v = make_uint4(a.x, a.y, b.x, b.y);
            if (f == 0) zu0.u = v; else if (f == 1) zu1.u = v;
            else if (f == 2) zu2.u = v; else zu3.u = v;
        }
    } else if (g == 1) {
        uint4 v = make_uint4(0x00003C00u, 0u, 0u, 0u);   // k8 = 1.0 (bias row)
        zu0.u = zu1.u = zu2.u = zu3.u = v;
    }

    float k0A=0.f,k1A=0.f,k2A=0.f,k3A=0.f;
    float k0B=0.f,k1B=0.f,k2B=0.f,k3B=0.f;
#pragma unroll
    for (int h = 0; h < H1; ++h) {
        int bh = Bh[h];
        float a0=0.f, a1=0.f, a2=0.f, a3=0.f;
#pragma unroll
        for (int tt = 0; tt < 8; ++tt) {
            int ct = h * 8 + tt;
            AU wu;
            wu.u = make_uint4(0u,0u,0u,0u);
            if (lane < 32) wu.u = BpL[ct*32 + lane];
            f32x4 z = {0.f, 0.f, 0.f, 0.f};
            f32x4 d0 = __builtin_amdgcn_mfma_f32_16x16x32_f16(wu.h, zu0.h, z, 0, 0, 0);
            f32x4 d1 = __builtin_amdgcn_mfma_f32_16x16x32_f16(wu.h, zu1.h, z, 0, 0, 0);
            f32x4 d2 = __builtin_amdgcn_mfma_f32_16x16x32_f16(wu.h, zu2.h, z, 0, 0, 0);
            f32x4 d3 = __builtin_amdgcn_mfma_f32_16x16x32_f16(wu.h, zu3.h, z, 0, 0, 0);
#pragma unroll
            for (int r = 0; r < 4; ++r) {
                float sel = ((tt*16 + r) + g4 < bh) ? 1.f : -1.f;
                a0 = fmaf(sel, fabsf(d0[r]), a0);
                a1 = fmaf(sel, fabsf(d1[r]), a1);
                a2 = fmaf(sel, fabsf(d2[r]), a2);
                a3 = fmaf(sel, fabsf(d3[r]), a3);
            }
        }
        a0 += __shfl_xor(a0, 16, 64); a0 += __shfl_xor(a0, 32, 64);
        a1 += __shfl_xor(a1, 16, 64); a1 += __shfl_xor(a1, 32, 64);
        a2 += __shfl_xor(a2, 16, 64); a2 += __shfl_xor(a2, 32, 64);
        a3 += __shfl_xor(a3, 16, 64); a3 += __shfl_xor(a3, 32, 64);
        bool p = (g == (h >> 1));
        if (h & 1) { k0B = p?a0:k0B; k1B = p?a1:k1B; k2B = p?a2:k2B; k3B = p?a3:k3B; }
        else       { k0A = p?a0:k0A; k1A = p?a1:k1A; k2A = p?a2:k2A; k3A = p?a3:k3A; }
    }

    // writeout: lane (cl,g) writes heads 2g,2g+1 for edges ebase + f*16 + cl
#pragma unroll
    for (int f = 0; f < 4; ++f) {
        int e0 = ebase + f*16 + cl;
        if (e0 < E_TOT) {
            int s, d;
            if (e0 < N_EDGES) { s = ei[e0]; d = ei[N_EDGES + e0]; }
            else { s = e0 - N_EDGES; d = s; }
            float2 ls = *(const float2*)(Ls + s*8 + 2*g);
            float2 lr = *(const float2*)(Lr + d*8 + 2*g);
            float kA = (f==0?k0A : f==1?k1A : f==2?k2A : k3A);
            float kB = (f==0?k0B : f==1?k1B : f==2?k2B : k3B);
            float2 o = make_float2(__expf(ls.x + lr.x + kA), __expf(ls.y + lr.y + kB));
            *(float2*)(e1 + (size_t)e0*8 + 2*g) = o;
        }
    }
}

// ---------------- layer-1 agg + f16 expand + relu + layer-2 transform ----------------
// 16 lanes per node; bucket CSR (beg = node*BSTRIDE, len = cnt[node])

#define AGG(hi, wv) { float W_ = (wv); ssum[hi] += W_; ag[hi].x += W_*xv.x; ag[hi].y += W_*xv.y; ag[hi].z += W_*xv.z; ag[hi].w += W_*xv.w; }

__global__ __launch_bounds__(256) void fused_agg1(
        const int* __restrict__ cnt, const int* __restrict__ elist,
        const int* __restrict__ slist,
        const float* __restrict__ e1, const float* __restrict__ x,
        const uint2* __restrict__ WAh, const unsigned* __restrict__ PBh,
        const uint4* __restrict__ W2P,
        const float* __restrict__ b2l, const float* __restrict__ b2r,
        float* __restrict__ xl2, float* __restrict__ xr2) {
    int tid = threadIdx.x;
    int node = blockIdx.x * 16 + (tid >> 4);
    int l = tid & 15;
    int beg = node * BSTRIDE, end = beg + cnt[node];

    float ssum[H1]; float4 ag[H1];
#pragma unroll
    for (int h = 0; h < H1; ++h) { ssum[h] = 0.f; ag[h] = make_float4(0.f,0.f,0.f,0.f); }

    for (int i = beg + l; i < end; i += 16) {
        int e = elist[i];
        const float4* p = (const float4*)(e1 + (size_t)e * 8);
        float4 wa = p[0], wb = p[1];
        float4 xv = ((const float4*)x)[slist[i]];
        AGG(0, wa.x) AGG(1, wa.y) AGG(2, wa.z) AGG(3, wa.w)
        AGG(4, wb.x) AGG(5, wb.y) AGG(6, wb.z) AGG(7, wb.w)
    }
#pragma unroll
    for (int off = 8; off; off >>= 1) {
#pragma unroll
        for (int h = 0; h < H1; ++h) {
            ssum[h] += __shfl_xor(ssum[h], off, 64);
            ag[h].x += __shfl_xor(ag[h].x, off, 64);
            ag[h].y += __shfl_xor(ag[h].y, off, 64);
            ag[h].z += __shfl_xor(ag[h].z, off, 64);
            ag[h].w += __shfl_xor(ag[h].w, off, 64);
        }
    }
    unsigned agA[H1], agB[H1], sg[H1];
#pragma unroll
    for (int h = 0; h < H1; ++h) {
        float inv = 1.f / (ssum[h] + 1e-16f);
        agA[h] = packh2(ag[h].x * inv, ag[h].y * inv);
        agB[h] = packh2(ag[h].z * inv, ag[h].w * inv);
        sg[h]  = packh2(ssum[h] * inv, 1.f);
    }

    float al0=0, al1=0, al2=0, al3=0, ar0=0, ar1=0, ar2=0, ar3=0;
#pragma unroll
    for (int h = 0; h < H1; ++h) {
        h2 ga = toh2(agA[h]), gb = toh2(agB[h]), gs = toh2(sg[h]);
#pragma unroll
        for (int j = 0; j < 4; ++j) {
            int u = l + 16*j;
            if (u < 60) {
                int c0 = h*C1 + u;
                uint2 wa0 = WAh[c0];      unsigned pb0 = PBh[c0];
                uint2 wa1 = WAh[c0 + 60]; unsigned pb1 = PBh[c0 + 60];
                float f0 = FDOT2(gs, toh2(pb0), 0.f);
                f0 = FDOT2(ga, toh2(wa0.x), f0);
                f0 = FDOT2(gb, toh2(wa0.y), f0);
                f0 = fmaxf(f0, 0.f);
                float f1 = FDOT2(gs, toh2(pb1), 0.f);
                f1 = FDOT2(ga, toh2(wa1.x), f1);
                f1 = FDOT2(gb, toh2(wa1.y), f1);
                f1 = fmaxf(f1, 0.f);
                h2 hp = toh2(packh2(f0, f1));
                int pi = (h*60 + u) * 2;
                uint4 wA = W2P[pi], wB = W2P[pi + 1];
                al0 = FDOT2(hp, toh2(wA.x), al0); al1 = FDOT2(hp, toh2(wA.y), al1);
                al2 = FDOT2(hp, toh2(wA.z), al2); al3 = FDOT2(hp, toh2(wA.w), al3);
                ar0 = FDOT2(hp, toh2(wB.x), ar0); ar1 = FDOT2(hp, toh2(wB.y), ar1);
                ar2 = FDOT2(hp, toh2(wB.z), ar2); ar3 = FDOT2(hp, toh2(wB.w), ar3);
            }
        }
    }
#pragma unroll
    for (int off = 8; off; off >>= 1) {
        al0 += __shfl_xor(al0, off, 64); al1 += __shfl_xor(al1, off, 64);
        al2 += __shfl_xor(al2, off, 64); al3 += __shfl_xor(al3, off, 64);
        ar0 += __shfl_xor(ar0, off, 64); ar1 += __shfl_xor(ar1, off, 64);
        ar2 += __shfl_xor(ar2, off, 64); ar3 += __shfl_xor(ar3, off, 64);
    }
    if (l == 0) {
        ((float4*)xl2)[node] = make_float4(al0 + b2l[0], al1 + b2l[1], al2 + b2l[2], al3 + b2l[3]);
        ((float4*)xr2)[node] = make_float4(ar0 + b2r[0], ar1 + b2r[1], ar2 + b2r[2], ar3 + b2r[3]);
    }
}

// ---------------- layer-2 fused attention ----------------

__global__ __launch_bounds__(256) void attn2(
        const int* __restrict__ cnt, const int* __restrict__ slist,
        const float* __restrict__ xl2, const float* __restrict__ xr2,
        const float* __restrict__ att2, const float* __restrict__ bias2,
        float* __restrict__ out) {
    int tid = threadIdx.x;
    int node = blockIdx.x * 16 + (tid >> 4);
    int l = tid & 15;
    int beg = node * BSTRIDE, end = beg + cnt[node];
    float4 xr = ((const float4*)xr2)[node];
    float a0 = att2[0], a1 = att2[1], a2 = att2[2], a3 = att2[3];

    float ssum = 0.f;
    float4 acc = make_float4(0.f, 0.f, 0.f, 0.f);
    for (int i = beg + l; i < end; i += 16) {
        float4 v = ((const float4*)xl2)[slist[i]];
        float lg = a0*lrelu(v.x + xr.x) + a1*lrelu(v.y + xr.y)
                 + a2*lrelu(v.z + xr.z) + a3*lrelu(v.w + xr.w);
        float w = __expf(lg);
        ssum += w;
        acc.x += w*v.x; acc.y += w*v.y; acc.z += w*v.z; acc.w += w*v.w;
    }
#pragma unroll
    for (int off = 8; off; off >>= 1) {
        ssum  += __shfl_xor(ssum,  off, 64);
        acc.x += __shfl_xor(acc.x, off, 64);
        acc.y += __shfl_xor(acc.y, off, 64);
        acc.z += __shfl_xor(acc.z, off, 64);
        acc.w += __shfl_xor(acc.w, off, 64);
    }
    if (l == 0) {
        float inv = 1.f / (ssum + 1e-16f);
        ((float4*)out)[node] = make_float4(acc.x*inv + bias2[0], acc.y*inv + bias2[1],
                                           acc.z*inv + bias2[2], acc.w*inv + bias2[3]);
    }
}

extern "C" void kernel_launch(void* const* d_in, const int* in_sizes, int n_in,
                              void* d_out, int out_size, void* d_ws, size_t ws_size,
                              hipStream_t stream) {
    const float* x     = (const float*)d_in[0];
    const int*   ei    = (const int*)  d_in[1];
    const float* W1l   = (const float*)d_in[2];
    const float* W1r   = (const float*)d_in[3];
    const float* b1l   = (const float*)d_in[4];
    const float* b1r   = (const float*)d_in[5];
    const float* att1  = (const float*)d_in[6];
    const float* bias1 = (const float*)d_in[7];
    const float* W2l   = (const float*)d_in[8];
    const float* W2r   = (const float*)d_in[9];
    const float* b2l   = (const float*)d_in[10];
    const float* b2r   = (const float*)d_in[11];
    const float* att2  = (const float*)d_in[12];
    const float* bias2 = (const float*)d_in[13];
    float* out = (float*)d_out;

    // workspace carve-up (segments 16B-aligned)
    float* e1   = (float*)d_ws;                   // E_TOT*8 = 1,360,000 f (EDGE order)
    float* Ls   = e1 + (size_t)E_TOT * 8;         // 80,000
    float* Lr   = Ls + 80000;                     // 80,000
    float* xl2  = Lr + 80000;                     // 40,000
    float* xr2  = xl2 + 40000;                    // 40,000
    unsigned* BpHu = (unsigned*)(xr2 + 40000);    // 8,192 (uint4[2048])
    int* Bh     = (int*)(BpHu + 8192);            // 16 (8 used)
    unsigned* WAhu = (unsigned*)(Bh + 16);        // 1,920 (uint2[960])
    unsigned* W2Pu = WAhu + 1920;                 // 7,680 (uint4[1920])
    unsigned* PBhu = W2Pu + 7680;                 // 960
    unsigned* xhu  = PBhu + 960;                  // 20,000 (uint2[10000])
    int* cnt    = (int*)(xhu + 20000);            // 10,000
    int* elist  = cnt + 10000;                    // N_NODES*BSTRIDE = 640,000
    int* slist  = elist + N_NODES * BSTRIDE;      // 640,000

    const int B = 256;

    prep<<<84, B, 0, stream>>>(
        x, W1l, W1r, b1l, b1r, att1, bias1, W2l, W2r,
        (uint4*)BpHu, Bh, (uint2*)WAhu, PBhu, (uint4*)W2Pu,
        (uint2*)xhu, Ls, Lr, cnt);

    logits_mfma<<<(E_TOT + 511) / 512, 512, 0, stream>>>(
        ei, (const uint2*)xhu, (const uint4*)BpHu, Bh, Ls, Lr,
        cnt, elist, slist, e1);
    fused_agg1<<<N_NODES / 16, B, 0, stream>>>(
        cnt, elist, slist, e1, x, (const uint2*)WAhu, PBhu, (const uint4*)W2Pu,
        b2l, b2r, xl2, xr2);
    attn2<<<N_NODES / 16, B, 0, stream>>>(cnt, slist, xl2, xr2, att2, bias2, out);
}

// Round 18
// 73.744 us; speedup vs baseline: 1.2064x; 1.2064x over previous
//
#include <hip/hip_runtime.h>

#define N_NODES 10000
#define N_EDGES 160000
#define E_TOT   170000   // + self loops
#define H1      8
#define C1      120
#define F1      960      // H1*C1
#define BSTRIDE 64       // bucket slots per node (max in-degree ~45 << 64)

typedef _Float16 h2 __attribute__((ext_vector_type(2)));
typedef _Float16 f16x8 __attribute__((ext_vector_type(8)));
typedef float f32x4 __attribute__((ext_vector_type(4)));
union H2U { unsigned u; h2 h; };
union AU  { uint4 u; f16x8 h; };

#if defined(__has_builtin)
#if __has_builtin(__builtin_amdgcn_fdot2)
#define FDOT2(a,b,c) __builtin_amdgcn_fdot2((a),(b),(c),false)
#endif
#endif
#ifndef FDOT2
#define FDOT2(a,b,c) ((float)(a)[0]*(float)(b)[0] + (float)(a)[1]*(float)(b)[1] + (c))
#endif

__device__ __forceinline__ float lrelu(float v) { return fmaxf(v, 0.2f * v); }
__device__ __forceinline__ unsigned packh2(float a, float b) {
    H2U u; u.h = (h2){(_Float16)a, (_Float16)b}; return u.u;
}
__device__ __forceinline__ h2 toh2(unsigned v) { H2U u; u.u = v; return u.h; }

// ---------------- fused prep ----------------
// blocks 0..3: zero own Bp range; t<240: |0.4*att|-folded sorted weight table,
//   Bh[h]=#pos; WAh/PBh (orig order); W2P (t<120).
// blocks 4..43: Ps computed 3-way-parallel (216 threads x 40 iters + combine);
//   250 nodes each: xh pack, Ls, Lr.
// blocks 44..83: zero cnt.
__global__ __launch_bounds__(256) void prep(
        const float* __restrict__ x,
        const float* __restrict__ W1l, const float* __restrict__ W1r,
        const float* __restrict__ b1l, const float* __restrict__ b1r,
        const float* __restrict__ att1, const float* __restrict__ bias1,
        const float* __restrict__ W2l, const float* __restrict__ W2r,
        uint4* __restrict__ BpH, int* __restrict__ Bh,
        uint2* __restrict__ WAh, unsigned* __restrict__ PBh,
        uint4* __restrict__ W2P,
        uint2* __restrict__ xh, float* __restrict__ Ls, float* __restrict__ Lr,
        int* __restrict__ cnt) {
    int b = blockIdx.x, t = threadIdx.x;
    if (b >= 44) {
        int i = (b - 44) * 256 + t;
        if (i < N_NODES) cnt[i] = 0;
        return;
    }
    if (b < 4) {
        // phase 0: zero this block's Bp range (512 uint4)
        BpH[b*512 + t]       = make_uint4(0u,0u,0u,0u);
        BpH[b*512 + 256 + t] = make_uint4(0u,0u,0u,0u);
        __syncthreads();
        if (t < 240) {
            int rc = b * 240 + t;
            int h = rc / C1, u = rc - h * C1;
            float a = att1[rc];
            int cntPos = 0, rankB = 0;
            for (int v = 0; v < C1; ++v) {
                bool pos = att1[h*C1 + v] > 0.f;
                cntPos += pos ? 1 : 0;
                rankB  += (v < u && pos) ? 1 : 0;
            }
            int newu = (a > 0.f) ? rankB : (cntPos + (u - rankB));
            float sc = fabsf(0.4f * a);
            float wl0 = W1l[rc], wl1 = W1l[F1+rc], wl2 = W1l[2*F1+rc], wl3 = W1l[3*F1+rc];
            float wr0 = W1r[rc], wr1 = W1r[F1+rc], wr2 = W1r[2*F1+rc], wr3 = W1r[3*F1+rc];
            float bc = b1l[rc] + b1r[rc];
            int pc2 = h * 128 + newu;
            int ct = pc2 >> 4, cl = pc2 & 15;
            BpH[ct*32 + cl] = make_uint4(packh2(sc*wl0, sc*wl1), packh2(sc*wl2, sc*wl3),
                                         packh2(sc*wr0, sc*wr1), packh2(sc*wr2, sc*wr3));
            BpH[ct*32 + 16 + cl] = make_uint4(packh2(sc*bc, 0.f), 0u, 0u, 0u);
            if (u == 0) Bh[h] = cntPos;
            WAh[rc] = make_uint2(packh2(wl0, wl1), packh2(wl2, wl3));
            PBh[rc] = packh2(b1l[rc], bias1[rc]);
        }
        if (t < 120) {
            int i = b * 120 + t;          // pair index: h = i/60, u = i%60
            int h = i / 60, u = i - h * 60;
            int c0 = h * C1 + u, c1 = c0 + 60;
            const float4 wl0 = ((const float4*)W2l)[c0], wl1 = ((const float4*)W2l)[c1];
            const float4 wr0 = ((const float4*)W2r)[c0], wr1 = ((const float4*)W2r)[c1];
            W2P[i*2]   = make_uint4(packh2(wl0.x, wl1.x), packh2(wl0.y, wl1.y),
                                    packh2(wl0.z, wl1.z), packh2(wl0.w, wl1.w));
            W2P[i*2+1] = make_uint4(packh2(wr0.x, wr1.x), packh2(wr0.y, wr1.y),
                                    packh2(wr0.z, wr1.z), packh2(wr0.w, wr1.w));
        }
        return;
    }
    // ---- node blocks: Ps via 3-way parallel partial sums ----
    __shared__ float Pp[3][72];
    __shared__ float Ps[72];
    {
        int o = t % 72, p = t / 72;   // output o, chunk p
        if (t < 216) {
            int h = o / 9, j = o % 9;
            float acc = 0.f;
            int u0 = p * 40;
            for (int u = u0; u < u0 + 40; ++u) {
                int c = h * C1 + u;
                float a = att1[c];
                float w;
                if (j < 4)      w = W1l[j * F1 + c];
                else if (j < 8) w = W1r[(j - 4) * F1 + c];
                else            w = b1l[c] + b1r[c];
                acc = fmaf(a, w, acc);
            }
            Pp[p][o] = acc;
        }
    }
    __syncthreads();
    if (t < 72) Ps[t] = 0.6f * (Pp[0][t] + Pp[1][t] + Pp[2][t]);
    __syncthreads();
    int n = (b - 4) * 250 + t;
    if (t < 250) {
        float4 xv = ((const float4*)x)[n];
        xh[n] = make_uint2(packh2(xv.x, xv.y), packh2(xv.z, xv.w));
#pragma unroll
        for (int h = 0; h < H1; ++h) {
            const float* p = Ps + h * 9;
            Ls[n*8+h] = xv.x*p[0] + xv.y*p[1] + xv.z*p[2] + xv.w*p[3];
            Lr[n*8+h] = xv.x*p[4] + xv.y*p[5] + xv.z*p[6] + xv.w*p[7] + p[8];
        }
    }
}

// ---------------- layer-1 logits: LDS-staged K=32 MFMA, 2 edge-frags/wave ----------------
// 512-thread blocks (8 waves, 256 edges). |att|-folded sorted table (32KB) in
// LDS; sign via posInHead < Bh[h]. All global gathers (xh, Ls, Lr) issued
// BEFORE the MFMA loop; s/d distributed via shfl (no ei reloads at writeout).

__global__ __launch_bounds__(512) void logits_mfma(
        const int* __restrict__ ei, const uint2* __restrict__ xh,
        const uint4* __restrict__ BpH, const int* __restrict__ Bh,
        const float* __restrict__ Ls, const float* __restrict__ Lr,
        int* __restrict__ cnt, int* __restrict__ elist, int* __restrict__ slist,
        float* __restrict__ e1) {
    __shared__ uint4 BpL[2048];   // 32 KB
    int tid = threadIdx.x;
#pragma unroll
    for (int i = 0; i < 4; ++i) BpL[tid + i*512] = BpH[tid + i*512];
    // fused bucket fill (independent work; all threads reach the barrier)
    {
        int ef = blockIdx.x * 256 + (tid & 255);
        if (tid < 256 && ef < E_TOT) {
            int s, d;
            if (ef < N_EDGES) { s = ei[ef]; d = ei[N_EDGES + ef]; }
            else { s = ef - N_EDGES; d = s; }
            int pos = atomicAdd(&cnt[d], 1);
            int slot = d * BSTRIDE + pos;
            elist[slot] = ef;
            slist[slot] = s;
        }
    }
    __syncthreads();

    int ebase = blockIdx.x * 256 + (tid >> 6) * 32;
    if (ebase >= E_TOT) return;
    int lane = tid & 63;
    int cl = lane & 15, g = lane >> 4;
    int g4 = g * 4;

    // gather phase: g0 lanes load s,d + xh for 2 fragments
    int s0 = 0, d0 = 0, s1 = 0, d1 = 0;
    AU zu0, zu1;
    zu0.u = zu1.u = make_uint4(0u,0u,0u,0u);
    if (g == 0) {
        {
            int er = ebase + cl;
            if (er >= E_TOT) er = E_TOT - 1;
            if (er < N_EDGES) { s0 = ei[er]; d0 = ei[N_EDGES + er]; }
            else { s0 = er - N_EDGES; d0 = s0; }
            uint2 a = xh[s0], bb = xh[d0];
            zu0.u = make_uint4(a.x, a.y, bb.x, bb.y);
        }
        {
            int er = ebase + 16 + cl;
            if (er >= E_TOT) er = E_TOT - 1;
            if (er < N_EDGES) { s1 = ei[er]; d1 = ei[N_EDGES + er]; }
            else { s1 = er - N_EDGES; d1 = s1; }
            uint2 a = xh[s1], bb = xh[d1];
            zu1.u = make_uint4(a.x, a.y, bb.x, bb.y);
        }
    } else if (g == 1) {
        uint4 v = make_uint4(0x00003C00u, 0u, 0u, 0u);   // k8 = 1.0 (bias row)
        zu0.u = zu1.u = v;
    }
    // distribute s/d to all g-groups and issue Ls/Lr gathers EARLY
    int s0a = __shfl(s0, cl, 64), d0a = __shfl(d0, cl, 64);
    int s1a = __shfl(s1, cl, 64), d1a = __shfl(d1, cl, 64);
    float2 ls0 = *(const float2*)(Ls + s0a*8 + 2*g);
    float2 lr0 = *(const float2*)(Lr + d0a*8 + 2*g);
    float2 ls1 = *(const float2*)(Ls + s1a*8 + 2*g);
    float2 lr1 = *(const float2*)(Lr + d1a*8 + 2*g);

    float kA0 = 0.f, kA1 = 0.f, kB0 = 0.f, kB1 = 0.f;
#pragma unroll
    for (int h = 0; h < H1; ++h) {
        int bh = Bh[h];
        float aa0 = 0.f, aa1 = 0.f;
#pragma unroll
        for (int tt = 0; tt < 8; ++tt) {
            int ct = h * 8 + tt;
            AU wu;
            wu.u = make_uint4(0u,0u,0u,0u);
            if (lane < 32) wu.u = BpL[ct*32 + lane];
            f32x4 z = {0.f, 0.f, 0.f, 0.f};
            f32x4 dd0 = __builtin_amdgcn_mfma_f32_16x16x32_f16(wu.h, zu0.h, z, 0, 0, 0);
            f32x4 dd1 = __builtin_amdgcn_mfma_f32_16x16x32_f16(wu.h, zu1.h, z, 0, 0, 0);
#pragma unroll
            for (int r = 0; r < 4; ++r) {
                float sel = ((tt*16 + r) + g4 < bh) ? 1.f : -1.f;
                aa0 = fmaf(sel, fabsf(dd0[r]), aa0);
                aa1 = fmaf(sel, fabsf(dd1[r]), aa1);
            }
        }
        aa0 += __shfl_xor(aa0, 16, 64); aa0 += __shfl_xor(aa0, 32, 64);
        aa1 += __shfl_xor(aa1, 16, 64); aa1 += __shfl_xor(aa1, 32, 64);
        bool p = (g == (h >> 1));
        if (h & 1) { kA1 = p ? aa0 : kA1; kB1 = p ? aa1 : kB1; }
        else       { kA0 = p ? aa0 : kA0; kB0 = p ? aa1 : kB0; }
    }

    // writeout (uses pre-gathered ls/lr; no global reloads)
    {
        int e0 = ebase + cl;
        if (e0 < E_TOT) {
            float2 o = make_float2(__expf(ls0.x + lr0.x + kA0), __expf(ls0.y + lr0.y + kA1));
            *(float2*)(e1 + (size_t)e0*8 + 2*g) = o;
        }
    }
    {
        int e1i = ebase + 16 + cl;
        if (e1i < E_TOT) {
            float2 o = make_float2(__expf(ls1.x + lr1.x + kB0), __expf(ls1.y + lr1.y + kB1));
            *(float2*)(e1 + (size_t)e1i*8 + 2*g) = o;
        }
    }
}

// ---------------- layer-1 agg + f16 expand + relu + layer-2 transform ----------------
// 16 lanes per node; bucket CSR (beg = node*BSTRIDE, len = cnt[node])

#define AGG(hi, wv) { float W_ = (wv); ssum[hi] += W_; ag[hi].x += W_*xv.x; ag[hi].y += W_*xv.y; ag[hi].z += W_*xv.z; ag[hi].w += W_*xv.w; }

__global__ __launch_bounds__(256) void fused_agg1(
        const int* __restrict__ cnt, const int* __restrict__ elist,
        const int* __restrict__ slist,
        const float* __restrict__ e1, const float* __restrict__ x,
        const uint2* __restrict__ WAh, const unsigned* __restrict__ PBh,
        const uint4* __restrict__ W2P,
        const float* __restrict__ b2l, const float* __restrict__ b2r,
        float* __restrict__ xl2, float* __restrict__ xr2) {
    int tid = threadIdx.x;
    int node = blockIdx.x * 16 + (tid >> 4);
    int l = tid & 15;
    int beg = node * BSTRIDE, end = beg + cnt[node];

    float ssum[H1]; float4 ag[H1];
#pragma unroll
    for (int h = 0; h < H1; ++h) { ssum[h] = 0.f; ag[h] = make_float4(0.f,0.f,0.f,0.f); }

    for (int i = beg + l; i < end; i += 16) {
        int e = elist[i];
        const float4* p = (const float4*)(e1 + (size_t)e * 8);
        float4 wa = p[0], wb = p[1];
        float4 xv = ((const float4*)x)[slist[i]];
        AGG(0, wa.x) AGG(1, wa.y) AGG(2, wa.z) AGG(3, wa.w)
        AGG(4, wb.x) AGG(5, wb.y) AGG(6, wb.z) AGG(7, wb.w)
    }
#pragma unroll
    for (int off = 8; off; off >>= 1) {
#pragma unroll
        for (int h = 0; h < H1; ++h) {
            ssum[h] += __shfl_xor(ssum[h], off, 64);
            ag[h].x += __shfl_xor(ag[h].x, off, 64);
            ag[h].y += __shfl_xor(ag[h].y, off, 64);
            ag[h].z += __shfl_xor(ag[h].z, off, 64);
            ag[h].w += __shfl_xor(ag[h].w, off, 64);
        }
    }
    unsigned agA[H1], agB[H1], sg[H1];
#pragma unroll
    for (int h = 0; h < H1; ++h) {
        float inv = 1.f / (ssum[h] + 1e-16f);
        agA[h] = packh2(ag[h].x * inv, ag[h].y * inv);
        agB[h] = packh2(ag[h].z * inv, ag[h].w * inv);
        sg[h]  = packh2(ssum[h] * inv, 1.f);
    }

    float al0=0, al1=0, al2=0, al3=0, ar0=0, ar1=0, ar2=0, ar3=0;
#pragma unroll
    for (int h = 0; h < H1; ++h) {
        h2 ga = toh2(agA[h]), gb = toh2(agB[h]), gs = toh2(sg[h]);
#pragma unroll
        for (int j = 0; j < 4; ++j) {
            int u = l + 16*j;
            if (u < 60) {
                int c0 = h*C1 + u;
                uint2 wa0 = WAh[c0];      unsigned pb0 = PBh[c0];
                uint2 wa1 = WAh[c0 + 60]; unsigned pb1 = PBh[c0 + 60];
                float f0 = FDOT2(gs, toh2(pb0), 0.f);
                f0 = FDOT2(ga, toh2(wa0.x), f0);
                f0 = FDOT2(gb, toh2(wa0.y), f0);
                f0 = fmaxf(f0, 0.f);
                float f1 = FDOT2(gs, toh2(pb1), 0.f);
                f1 = FDOT2(ga, toh2(wa1.x), f1);
                f1 = FDOT2(gb, toh2(wa1.y), f1);
                f1 = fmaxf(f1, 0.f);
                h2 hp = toh2(packh2(f0, f1));
                int pi = (h*60 + u) * 2;
                uint4 wA = W2P[pi], wB = W2P[pi + 1];
                al0 = FDOT2(hp, toh2(wA.x), al0); al1 = FDOT2(hp, toh2(wA.y), al1);
                al2 = FDOT2(hp, toh2(wA.z), al2); al3 = FDOT2(hp, toh2(wA.w), al3);
                ar0 = FDOT2(hp, toh2(wB.x), ar0); ar1 = FDOT2(hp, toh2(wB.y), ar1);
                ar2 = FDOT2(hp, toh2(wB.z), ar2); ar3 = FDOT2(hp, toh2(wB.w), ar3);
            }
        }
    }
#pragma unroll
    for (int off = 8; off; off >>= 1) {
        al0 += __shfl_xor(al0, off, 64); al1 += __shfl_xor(al1, off, 64);
        al2 += __shfl_xor(al2, off, 64); al3 += __shfl_xor(al3, off, 64);
        ar0 += __shfl_xor(ar0, off, 64); ar1 += __shfl_xor(ar1, off, 64);
        ar2 += __shfl_xor(ar2, off, 64); ar3 += __shfl_xor(ar3, off, 64);
    }
    if (l == 0) {
        ((float4*)xl2)[node] = make_float4(al0 + b2l[0], al1 + b2l[1], al2 + b2l[2], al3 + b2l[3]);
        ((float4*)xr2)[node] = make_float4(ar0 + b2r[0], ar1 + b2r[1], ar2 + b2r[2], ar3 + b2r[3]);
    }
}

// ---------------- layer-2 fused attention ----------------

__global__ __launch_bounds__(256) void attn2(
        const int* __restrict__ cnt, const int* __restrict__ slist,
        const float* __restrict__ xl2, const float* __restrict__ xr2,
        const float* __restrict__ att2, const float* __restrict__ bias2,
        float* __restrict__ out) {
    int tid = threadIdx.x;
    int node = blockIdx.x * 16 + (tid >> 4);
    int l = tid & 15;
    int beg = node * BSTRIDE, end = beg + cnt[node];
    float4 xr = ((const float4*)xr2)[node];
    float a0 = att2[0], a1 = att2[1], a2 = att2[2], a3 = att2[3];

    float ssum = 0.f;
    float4 acc = make_float4(0.f, 0.f, 0.f, 0.f);
    for (int i = beg + l; i < end; i += 16) {
        float4 v = ((const float4*)xl2)[slist[i]];
        float lg = a0*lrelu(v.x + xr.x) + a1*lrelu(v.y + xr.y)
                 + a2*lrelu(v.z + xr.z) + a3*lrelu(v.w + xr.w);
        float w = __expf(lg);
        ssum += w;
        acc.x += w*v.x; acc.y += w*v.y; acc.z += w*v.z; acc.w += w*v.w;
    }
#pragma unroll
    for (int off = 8; off; off >>= 1) {
        ssum  += __shfl_xor(ssum,  off, 64);
        acc.x += __shfl_xor(acc.x, off, 64);
        acc.y += __shfl_xor(acc.y, off, 64);
        acc.z += __shfl_xor(acc.z, off, 64);
        acc.w += __shfl_xor(acc.w, off, 64);
    }
    if (l == 0) {
        float inv = 1.f / (ssum + 1e-16f);
        ((float4*)out)[node] = make_float4(acc.x*inv + bias2[0], acc.y*inv + bias2[1],
                                           acc.z*inv + bias2[2], acc.w*inv + bias2[3]);
    }
}

extern "C" void kernel_launch(void* const* d_in, const int* in_sizes, int n_in,
                              void* d_out, int out_size, void* d_ws, size_t ws_size,
                              hipStream_t stream) {
    const float* x     = (const float*)d_in[0];
    const int*   ei    = (const int*)  d_in[1];
    const float* W1l   = (const float*)d_in[2];
    const float* W1r   = (const float*)d_in[3];
    const float* b1l   = (const float*)d_in[4];
    const float* b1r   = (const float*)d_in[5];
    const float* att1  = (const float*)d_in[6];
    const float* bias1 = (const float*)d_in[7];
    const float* W2l   = (const float*)d_in[8];
    const float* W2r   = (const float*)d_in[9];
    const float* b2l   = (const float*)d_in[10];
    const float* b2r   = (const float*)d_in[11];
    const float* att2  = (const float*)d_in[12];
    const float* bias2 = (const float*)d_in[13];
    float* out = (float*)d_out;

    // workspace carve-up (segments 16B-aligned)
    float* e1   = (float*)d_ws;                   // E_TOT*8 = 1,360,000 f (EDGE order)
    float* Ls   = e1 + (size_t)E_TOT * 8;         // 80,000
    float* Lr   = Ls + 80000;                     // 80,000
    float* xl2  = Lr + 80000;                     // 40,000
    float* xr2  = xl2 + 40000;                    // 40,000
    unsigned* BpHu = (unsigned*)(xr2 + 40000);    // 8,192 (uint4[2048])
    int* Bh     = (int*)(BpHu + 8192);            // 16 (8 used)
    unsigned* WAhu = (unsigned*)(Bh + 16);        // 1,920 (uint2[960])
    unsigned* W2Pu = WAhu + 1920;                 // 7,680 (uint4[1920])
    unsigned* PBhu = W2Pu + 7680;                 // 960
    unsigned* xhu  = PBhu + 960;                  // 20,000 (uint2[10000])
    int* cnt    = (int*)(xhu + 20000);            // 10,000
    int* elist  = cnt + 10000;                    // N_NODES*BSTRIDE = 640,000
    int* slist  = elist + N_NODES * BSTRIDE;      // 640,000

    const int B = 256;

    prep<<<84, B, 0, stream>>>(
        x, W1l, W1r, b1l, b1r, att1, bias1, W2l, W2r,
        (uint4*)BpHu, Bh, (uint2*)WAhu, PBhu, (uint4*)W2Pu,
        (uint2*)xhu, Ls, Lr, cnt);

    logits_mfma<<<(E_TOT + 255) / 256, 512, 0, stream>>>(
        ei, (const uint2*)xhu, (const uint4*)BpHu, Bh, Ls, Lr,
        cnt, elist, slist, e1);
    fused_agg1<<<N_NODES / 16, B, 0, stream>>>(
        cnt, elist, slist, e1, x, (const uint2*)WAhu, PBhu, (const uint4*)W2Pu,
        b2l, b2r, xl2, xr2);
    attn2<<<N_NODES / 16, B, 0, stream>>>(cnt, slist, xl2, xr2, att2, bias2, out);
}